// Round 13
// baseline (292.104 us; speedup 1.0000x reference)
//
#include <hip/hip_runtime.h>

// SigWassersteinMetric: depth-4 path signature, C=10, T=256.
//   original: (4096, 256, 10) f32; generated: (1024, 256, 10) f32; sample_idx: (1024,)
//
// ROUND-27 == ROUND-26 resubmitted verbatim (R12 bench died on container
// acquisition, not on the kernel: no pytest verdict, no counters).
//
// ROUND-26: lane-varying reads moved to the VMEM pipe (vmcnt != lgkmcnt).
//   - R25: accum 192 (= LDS-pipe ceiling: 6 LDS insts ~57cyc x32 waves = 1824
//     cyc/CU-step), residual 87us fixed. Only lever left is the accum loop.
//   - Failed migrations: SMEM (R18, lgkmcnt conflation), VALU cndmask
//     (R19/R20, conversion tax). Untried idle pipe: VMEM (per-lane global
//     loads, own counter, compiler pipelines well; HBM at 7%).
//   - Each block writes dx scratch (plain rows + (v[k],v[k+5]) pair rows,
//     96B stride) into the FIRST 6120 floats of its own ws row slot (row is
//     written only in the epilogue, after a pre-epilogue __syncthreads ->
//     safe aliasing, zero extra ws). Hot loop: vjp + vk from GLOBAL
//     (dwordx2, L1/L2-resident), va/vb/vc/via stay on LDS.
//       LDS:  38cyc x32 = 1216 ; VALU: ~170x8 = 1360 (binds) -> ideal 145us
//   - Fallback small-ws modes keep the pure-LDS loop (template<GVM>).
//   - Prediction: accum ~155-175, VALUBusy ~85%, WRITE +45MB, total 245-265.
//     If accum >= 185: VMEM latency tax -> revert R25, declare floor.
//
// Horner-factored Chen step (verified rounds 2/4-13):
//   A2 = S2 + (S1 + v/4) (x) v/3 ;  B2 = S2 + (S1 + v/3) (x) v/2
//   A3 = S3 + A2 (x) v/2 ;  S4' = S4 + A3 (x) v ;  S3' = S3 + B2 (x) v
//   S2' = S2 + (S1 + v/2) (x) v ;  S1 closed-form in epilogue.
#define T_LEN 256
#define C_DIM 10
#define NSTEP 255
#define BSZ   1024
#define NPAIR 1024
#define D1 10
#define D2 100
#define D3 1000
#define DTOT 11110
#define PATH_ELEMS (T_LEN * C_DIM)   // 2560
#define DX_ELEMS (NSTEP * C_DIM)     // 2550
#define DXROW 12                     // padded LDS dx row stride (48 B)
#define GROW 24                      // global scratch row stride (96 B)
                                     // [0..9]=v, [12..21]=(v[k],v[k+5]) pairs
#define GSCR_FLOATS (NSTEP * GROW)   // 6120 < DTOT -> fits in own row slot

typedef float f32x2 __attribute__((ext_vector_type(2)));
typedef float f32x4 __attribute__((ext_vector_type(4)));

// d += bcast(a.lo) * b
#define PK_FMA_B0(d, a, b) \
    asm("v_pk_fma_f32 %0, %1, %2, %0 op_sel:[0,0,0] op_sel_hi:[0,1,1]" \
        : "+v"(d) : "v"(a), "v"(b))
// d += bcast(a.hi) * b
#define PK_FMA_B1(d, a, b) \
    asm("v_pk_fma_f32 %0, %1, %2, %0 op_sel:[1,0,0] op_sel_hi:[1,1,1]" \
        : "+v"(d) : "v"(a), "v"(b))
// d = bcast(a.lo) * b + c
#define PK_FMA_B0N(d, a, b, c) \
    asm("v_pk_fma_f32 %0, %1, %2, %3 op_sel:[0,0,0] op_sel_hi:[0,1,1]" \
        : "=v"(d) : "v"(a), "v"(b), "v"(c))
// d = bcast(a.hi) * b + c
#define PK_FMA_B1N(d, a, b, c) \
    asm("v_pk_fma_f32 %0, %1, %2, %3 op_sel:[1,0,0] op_sel_hi:[1,1,1]" \
        : "=v"(d) : "v"(a), "v"(b), "v"(c))
// d = a * bcast(b.lo) + c   (src1 broadcast)
#define PK_FMA_S1B0N(d, a, b, c) \
    asm("v_pk_fma_f32 %0, %1, %2, %3 op_sel:[0,0,0] op_sel_hi:[1,0,1]" \
        : "=v"(d) : "v"(a), "v"(b), "v"(c))
// d = a * bcast(b.hi) + c
#define PK_FMA_S1B1N(d, a, b, c) \
    asm("v_pk_fma_f32 %0, %1, %2, %3 op_sel:[0,1,0] op_sel_hi:[1,1,1]" \
        : "=v"(d) : "v"(a), "v"(b), "v"(c))
// d += a * bcast(b.lo)
#define PK_FMA_S1B0(d, a, b) \
    asm("v_pk_fma_f32 %0, %1, %2, %0 op_sel:[0,0,0] op_sel_hi:[1,0,1]" \
        : "+v"(d) : "v"(a), "v"(b))
// d += a * bcast(b.hi)
#define PK_FMA_S1B1(d, a, b) \
    asm("v_pk_fma_f32 %0, %1, %2, %0 op_sel:[0,1,0] op_sel_hi:[1,1,1]" \
        : "+v"(d) : "v"(a), "v"(b))
// d = a * 0.5 (both halves)
#define PK_MUL_HALF(d, a) \
    asm("v_pk_mul_f32 %0, %1, 0.5 op_sel:[0,0] op_sel_hi:[1,0]" \
        : "=v"(d) : "v"(a))

template<int GVM>
__global__ __launch_bounds__(256)
void sig_accum_kernel(
    const float* __restrict__ original,
    const float* __restrict__ generated,
    const int* __restrict__ sample_idx,
    float* __restrict__ ws,
    float* __restrict__ accinit,   // non-null: block 0 zeroes DTOT+2 floats
    int nrep, int store_mode)
{
    const int tid  = threadIdx.x;
    const int bp   = blockIdx.x;         // 0 .. 2*NPAIR-1
    const int b    = bp >> 1;            // pair index
    const int pass = bp & 1;             // 0 = generated (-), 1 = original (+)
    const float sgn = pass ? 1.0f : -1.0f;

    __shared__ __align__(16) float s_dx[NSTEP * DXROW];  // 12240 B

    if (accinit != nullptr && bp == 0) {
        for (int i = tid; i < DTOT + 2; i += 256) accinit[i] = 0.0f;
    }

    const float* path = pass
        ? original + (size_t)sample_idx[b] * PATH_ELEMS
        : generated + (size_t)b * PATH_ELEMS;

    // Global scratch aliased into this block's OWN row slot (row written
    // only after the pre-epilogue barrier).
    float* gscr = ws + (size_t)bp * DTOT;

    for (int idx = tid; idx < DX_ELEMS; idx += 256) {
        int t = idx / C_DIM, c = idx - t * C_DIM;
        const float v = path[idx + C_DIM] - path[idx];
        s_dx[t * DXROW + c] = v;
        if (GVM) gscr[t * GROW + c] = v;            // plain section
    }
    __syncthreads();
    if (GVM) {
        // Pair section: (v[k], v[k+5]) at [12 + 2k], from staged LDS.
        for (int idx = tid; idx < NSTEP * 5; idx += 256) {
            int t = idx / 5, k = idx - t * 5;
            f32x2 pv;
            pv.x = s_dx[t * DXROW + k];
            pv.y = s_dx[t * DXROW + k + 5];
            *(f32x2*)&gscr[t * GROW + 12 + 2 * k] = pv;
        }
        __syncthreads();   // drains scratch stores (vmcnt 0 before barrier)
    }

    const int mbase = 2 * tid;               // valid tid<250
    const int k0  = mbase / 100;             // 0..4
    const int ij0 = mbase - k0 * 100;        // even
    const int ia  = ij0 / 10;
    const int j0  = ij0 - ia * 10;           // even -> (j0, j0+1) same decade

    float s1a = 0.0f;
    f32x2 s2p = {0.0f, 0.0f};                 // (q0, q1)
    f32x2 s3p[2] = {{0.0f, 0.0f}, {0.0f, 0.0f}};  // [0]=(q0,q1)@k0, [1]=@k1
    f32x2 acc2[4][5];                         // [0]=q0k0 [1]=q1k0 [2]=q0k1 [3]=q1k1
    #pragma unroll
    for (int r = 0; r < 4; ++r)
        #pragma unroll
        for (int i = 0; i < 5; ++i) acc2[r][i] = (f32x2){0.0f, 0.0f};

    if (tid < 250) {
        const float* vrow = s_dx;
        const float* pj = gscr + j0;              // vjp source (VMEM)
        const float* pk = gscr + 12 + 2 * k0;     // vk pair source (VMEM)
        #pragma unroll 2
        for (int t = 0; t < NSTEP; ++t, vrow += DXROW, pj += GROW, pk += GROW) {
            const f32x4 va = *(const f32x4*)(vrow);        // v0..v3 (LDS uniform)
            const f32x4 vb = *(const f32x4*)(vrow + 4);    // v4..v7 (LDS uniform)
            const f32x2 vc = *(const f32x2*)(vrow + 8);    // v8,v9  (LDS uniform)
            const float via = vrow[ia];                    // LDS b32 (prefix chain)
            f32x2 vjp, vkp;
            if (GVM) {
                vjp = *(const f32x2*)(pj);                 // global dwordx2
                vkp = *(const f32x2*)(pk);                 // global dwordx2
            } else {
                vjp = *(const f32x2*)(vrow + j0);
                vkp.x = vrow[k0];
                vkp.y = vrow[k0 + 5];
            }

            const f32x2 vv2[5] = {va.xy, va.zw, vb.xy, vb.zw, vc};

            // scalar prefix terms
            const float t3  = fmaf(via, 0.5f, s1a);
            const float t1b = fmaf(via, 0.25f, s1a) * (1.0f / 3.0f);
            const float t2b = fmaf(via, (1.0f / 3.0f), s1a) * 0.5f;
            f32x2 pA; pA.x = t1b; pA.y = t2b;
            f32x2 pT; pT.x = t3;  pT.y = t3;

            f32x2 vkhp;                       // (vk0*0.5, vk1*0.5)
            PK_MUL_HALF(vkhp, vkp);

            // level 2 (q-pairs)
            f32x2 a2p, b2p;
            PK_FMA_B0N(a2p, pA, vjp, s2p);    // a2_q = t1b*vj_q + s2_q
            PK_FMA_B1N(b2p, pA, vjp, s2p);    // b2_q = t2b*vj_q + s2_q
            PK_FMA_B0(s2p, pT, vjp);          // s2_q += t3*vj_q

            // level 3 (q-pairs, k-channel broadcast from vkp/vkhp halves)
            f32x2 a3xp, a3yp;
            PK_FMA_S1B0N(a3xp, a2p, vkhp, s3p[0]);  // a3_q@k0
            PK_FMA_S1B1N(a3yp, a2p, vkhp, s3p[1]);  // a3_q@k1
            PK_FMA_S1B0(s3p[0], b2p, vkp);          // s3_q@k0 += b2_q*vk0
            PK_FMA_S1B1(s3p[1], b2p, vkp);          // s3_q@k1 += b2_q*vk1

            // level 4: 20 pk-FMAs (a3 broadcast from pair halves)
            #pragma unroll
            for (int i = 0; i < 5; ++i) {
                PK_FMA_B0(acc2[0][i], a3xp, vv2[i]);
                PK_FMA_B1(acc2[1][i], a3xp, vv2[i]);
                PK_FMA_B0(acc2[2][i], a3yp, vv2[i]);
                PK_FMA_B1(acc2[3][i], a3yp, vv2[i]);
            }
            s1a += via;
        }
    }

    if (GVM) __syncthreads();   // all scratch reads done before row overwrite

    // ---- Epilogue: signed single-path row ----
    if (store_mode) {
        float* row = ws + (size_t)bp * DTOT;
        if (tid < D1)
            row[tid] = sgn * (path[(T_LEN - 1) * C_DIM + tid] - path[tid]);
        if (tid < 50) {       // k0 == 0 threads own ij0 = 2*tid
            row[D1 + ij0]     = sgn * s2p[0];
            row[D1 + ij0 + 1] = sgn * s2p[1];
        }
        if (tid < 250) {
            #pragma unroll
            for (int ch = 0; ch < 2; ++ch) {          // ch=0 -> k0, ch=1 -> k0+5
                const int kk = k0 + 5 * ch;
                #pragma unroll
                for (int q = 0; q < 2; ++q) {
                    const int idx3 = (ij0 + q) * 10 + kk;
                    row[D1 + D2 + idx3] = sgn * s3p[ch][q];
                    float* p4 = row + D1 + D2 + D3 + (size_t)idx3 * 10;
                    #pragma unroll
                    for (int i = 0; i < 5; ++i)
                        *(f32x2*)&p4[2 * i] = sgn * acc2[ch * 2 + q][i];
                }
            }
        }
    } else {
        float* base = ws + (size_t)(b % nrep) * DTOT;
        if (tid < D1)
            atomicAdd(&base[tid],
                      sgn * (path[(T_LEN - 1) * C_DIM + tid] - path[tid]));
        if (tid < 50) {
            atomicAdd(&base[D1 + ij0],     sgn * s2p[0]);
            atomicAdd(&base[D1 + ij0 + 1], sgn * s2p[1]);
        }
        if (tid < 250) {
            #pragma unroll
            for (int ch = 0; ch < 2; ++ch) {
                const int kk = k0 + 5 * ch;
                #pragma unroll
                for (int q = 0; q < 2; ++q) {
                    const int idx3 = (ij0 + q) * 10 + kk;
                    atomicAdd(&base[D1 + D2 + idx3], sgn * s3p[ch][q]);
                    #pragma unroll
                    for (int l = 0; l < 10; ++l)
                        atomicAdd(&base[D1 + D2 + D3 + idx3 * 10 + l],
                                  sgn * acc2[ch * 2 + q][l >> 1][l & 1]);
                }
            }
        }
    }
}

// Stage 1: block sums 32 rows for a float2 d-tile (coalesced), atomically
// accumulates into accvec[DTOT]. Grid: (ceil(5555/256), nrows/32). NO fences.
__global__ __launch_bounds__(256) void sig_sum_kernel(
    const float* __restrict__ ws, float* __restrict__ accvec)
{
    const int d2 = blockIdx.x * 256 + threadIdx.x;   // DTOT/2 = 5555
    if (d2 >= DTOT / 2) return;
    const float* p = ws + (size_t)(blockIdx.y * 32) * DTOT + 2 * d2;
    float sx = 0.0f, sy = 0.0f;
    #pragma unroll
    for (int r = 0; r < 32; ++r) {
        const float2 v = *(const float2*)(p + (size_t)r * DTOT);
        sx += v.x; sy += v.y;
    }
    atomicAdd(&accvec[2 * d2], sx);
    atomicAdd(&accvec[2 * d2 + 1], sy);
}

// Stage 2: sum of squares -> sumsq; last block writes the norm.
__global__ __launch_bounds__(256) void sig_sumsq_kernel(
    const float* __restrict__ accvec, float* __restrict__ sumsq,
    unsigned int* __restrict__ counter, float* __restrict__ out, int nblocks)
{
    const int d = blockIdx.x * 256 + threadIdx.x;
    float s = 0.0f;
    if (d < DTOT) { float v = accvec[d]; s = v * v; }
    for (int off = 32; off > 0; off >>= 1) s += __shfl_down(s, off, 64);
    __shared__ float red[4];
    __shared__ unsigned int lastflag;
    if ((threadIdx.x & 63) == 0) red[threadIdx.x >> 6] = s;
    __syncthreads();
    if (threadIdx.x == 0) {
        atomicAdd(sumsq, red[0] + red[1] + red[2] + red[3]);
        __threadfence();
        lastflag = (atomicAdd(counter, 1u) == (unsigned int)(nblocks - 1));
    }
    __syncthreads();
    if (threadIdx.x == 0 && lastflag) {
        __threadfence();
        out[0] = sqrtf(*(volatile float*)sumsq) * (1.0f / (float)BSZ);
    }
}

// Fallback reduce for small-ws atomic-replica modes.
__global__ __launch_bounds__(256) void sig_reduce_kernel(
    const float* __restrict__ ws, int nrows, float* __restrict__ sumsq,
    unsigned int* __restrict__ counter, float* __restrict__ out, int nblocks)
{
    const int d = blockIdx.x * 256 + threadIdx.x;
    float s = 0.0f;
    if (d < DTOT) {
        for (int r = 0; r < nrows; ++r) s += ws[(size_t)r * DTOT + d];
        s = s * s;
    }
    for (int off = 32; off > 0; off >>= 1) s += __shfl_down(s, off, 64);
    __shared__ float red[4];
    __shared__ unsigned int lastflag;
    if ((threadIdx.x & 63) == 0) red[threadIdx.x >> 6] = s;
    __syncthreads();
    if (threadIdx.x == 0) {
        atomicAdd(sumsq, red[0] + red[1] + red[2] + red[3]);
        __threadfence();
        lastflag = (atomicAdd(counter, 1u) == (unsigned int)(nblocks - 1));
    }
    __syncthreads();
    if (threadIdx.x == 0 && lastflag) {
        __threadfence();
        out[0] = sqrtf(*(volatile float*)sumsq) * (1.0f / (float)BSZ);
    }
}

extern "C" void kernel_launch(void* const* d_in, const int* in_sizes, int n_in,
                              void* d_out, int out_size, void* d_ws, size_t ws_size,
                              hipStream_t stream) {
    const float* original   = (const float*)d_in[0];
    const float* generated  = (const float*)d_in[1];
    const int*   sample_idx = (const int*)d_in[2];
    float* out = (float*)d_out;
    float* ws  = (float*)d_ws;

    // Layouts:
    //  split: rows [0, 2N*DTOT), accvec [+DTOT), sumsq [+1), counter [+1)
    //  store: rows [0, N*DTOT),  accvec [+DTOT), sumsq [+1), counter [+1)
    const size_t need_split = ((size_t)(2 * NPAIR + 1) * DTOT + 2) * sizeof(float);
    const size_t need_store = ((size_t)(NPAIR + 1) * DTOT + 2) * sizeof(float);

    if (ws_size >= need_split) {
        // Primary: 3 dispatches. accum block 0 zero-inits accvec+sumsq+counter;
        // VMEM-offload loop (scratch aliased inside each block's row slot).
        float* accvec = ws + (size_t)2 * NPAIR * DTOT;
        float* sumsq  = accvec + DTOT;
        unsigned int* counter = (unsigned int*)(sumsq + 1);
        sig_accum_kernel<1><<<2 * NPAIR, 256, 0, stream>>>(original, generated,
                                                           sample_idx, ws, accvec,
                                                           1, 1);
        dim3 g1((DTOT / 2 + 255) / 256, 2 * NPAIR / 32);
        sig_sum_kernel<<<g1, 256, 0, stream>>>(ws, accvec);
        const int nb2 = (DTOT + 255) / 256;
        sig_sumsq_kernel<<<nb2, 256, 0, stream>>>(accvec, sumsq, counter, out, nb2);
    } else if (ws_size >= need_store) {
        // Pair-atomic rows + separate reduction (pure-LDS loop).
        float* accvec = ws + (size_t)NPAIR * DTOT;
        float* sumsq  = accvec + DTOT;
        unsigned int* counter = (unsigned int*)(sumsq + 1);
        hipMemsetAsync(ws, 0, need_store, stream);
        sig_accum_kernel<0><<<2 * NPAIR, 256, 0, stream>>>(original, generated,
                                                           sample_idx, ws, nullptr,
                                                           NPAIR, 0);
        dim3 g1((DTOT / 2 + 255) / 256, NPAIR / 32);
        sig_sum_kernel<<<g1, 256, 0, stream>>>(ws, accvec);
        const int nb2 = (DTOT + 255) / 256;
        sig_sumsq_kernel<<<nb2, 256, 0, stream>>>(accvec, sumsq, counter, out, nb2);
    } else {
        int nrep = 1;
        if (ws_size >= ((size_t)64 * DTOT + 2) * sizeof(float)) nrep = 64;
        else if (ws_size >= ((size_t)8 * DTOT + 2) * sizeof(float)) nrep = 8;
        float* sumsq = ws + (size_t)nrep * DTOT;
        unsigned int* counter = (unsigned int*)(sumsq + 1);
        hipMemsetAsync(ws, 0, ((size_t)nrep * DTOT + 2) * sizeof(float), stream);
        sig_accum_kernel<0><<<2 * NPAIR, 256, 0, stream>>>(original, generated,
                                                           sample_idx, ws, nullptr,
                                                           nrep, 0);
        const int nb2 = (DTOT + 255) / 256;
        sig_reduce_kernel<<<nb2, 256, 0, stream>>>(ws, nrep, sumsq, counter, out, nb2);
    }
}

// Round 14
// 278.567 us; speedup vs baseline: 1.0486x; 1.0486x over previous
//
#include <hip/hip_runtime.h>

// SigWassersteinMetric: depth-4 path signature, C=10, T=256.
//   original: (4096, 256, 10) f32; generated: (1024, 256, 10) f32; sample_idx: (1024,)
//
// ROUND-28: LDS column-pair layouts -- fewer LDS cycles per step, SAME pipe.
//   - R26/27 FAILED (217us, kill-rule hit): VMEM scratch cost > LDS saved.
//     5 failed migrations total => never move lane reads off LDS; instead
//     cut LDS cycles by layout.
//   - vk (2xb32=11.6cyc) and vjp (b64=8cyc) become 2-step b128 reads (6cyc/
//     step each) from pair layouts staged once per block:
//       s_pk[k][t]   = (v[t][k], v[t][k+5])     k=0..4
//       s_pj[j2][t]  = (v[t][2j2], v[t][2j2+1]) j2=0..4
//     stride 258 f32x2 (2064B): 16B-aligned b128 at even t, bases on
//     distinct bank quads (j2*516 %32 = 4*j2) -> conflict-free.
//   - Per wave-step: 32 uniform + 5.8 via + 6 + 6 = 49.8 cyc (was 57.4).
//     LDS 32.9KB/block -> 4 blocks/CU, 16 waves (4/SIMD, R14-precedent OK).
//     Model: 8blk x255 x4w x49.8 = 406K cyc = 169us ideal; VALU 141 no bind.
//   - Prediction: accum 172-185, total 262-272. KILL: accum>=190 -> revert
//     R25, declare floor.
//
// Horner-factored Chen step (verified rounds 2/4-13):
//   A2 = S2 + (S1 + v/4) (x) v/3 ;  B2 = S2 + (S1 + v/3) (x) v/2
//   A3 = S3 + A2 (x) v/2 ;  S4' = S4 + A3 (x) v ;  S3' = S3 + B2 (x) v
//   S2' = S2 + (S1 + v/2) (x) v ;  S1 closed-form in epilogue.
#define T_LEN 256
#define C_DIM 10
#define NSTEP 255
#define BSZ   1024
#define NPAIR 1024
#define D1 10
#define D2 100
#define D3 1000
#define DTOT 11110
#define PATH_ELEMS (T_LEN * C_DIM)   // 2560
#define DX_ELEMS (NSTEP * C_DIM)     // 2550
#define DXROW 12                     // padded LDS dx row stride (48 B)
#define PSTRIDE 258                  // pair-layout column stride (f32x2 units)

typedef float f32x2 __attribute__((ext_vector_type(2)));
typedef float f32x4 __attribute__((ext_vector_type(4)));

// d += bcast(a.lo) * b
#define PK_FMA_B0(d, a, b) \
    asm("v_pk_fma_f32 %0, %1, %2, %0 op_sel:[0,0,0] op_sel_hi:[0,1,1]" \
        : "+v"(d) : "v"(a), "v"(b))
// d += bcast(a.hi) * b
#define PK_FMA_B1(d, a, b) \
    asm("v_pk_fma_f32 %0, %1, %2, %0 op_sel:[1,0,0] op_sel_hi:[1,1,1]" \
        : "+v"(d) : "v"(a), "v"(b))
// d = bcast(a.lo) * b + c
#define PK_FMA_B0N(d, a, b, c) \
    asm("v_pk_fma_f32 %0, %1, %2, %3 op_sel:[0,0,0] op_sel_hi:[0,1,1]" \
        : "=v"(d) : "v"(a), "v"(b), "v"(c))
// d = bcast(a.hi) * b + c
#define PK_FMA_B1N(d, a, b, c) \
    asm("v_pk_fma_f32 %0, %1, %2, %3 op_sel:[1,0,0] op_sel_hi:[1,1,1]" \
        : "=v"(d) : "v"(a), "v"(b), "v"(c))
// d = a * bcast(b.lo) + c   (src1 broadcast)
#define PK_FMA_S1B0N(d, a, b, c) \
    asm("v_pk_fma_f32 %0, %1, %2, %3 op_sel:[0,0,0] op_sel_hi:[1,0,1]" \
        : "=v"(d) : "v"(a), "v"(b), "v"(c))
// d = a * bcast(b.hi) + c
#define PK_FMA_S1B1N(d, a, b, c) \
    asm("v_pk_fma_f32 %0, %1, %2, %3 op_sel:[0,1,0] op_sel_hi:[1,1,1]" \
        : "=v"(d) : "v"(a), "v"(b), "v"(c))
// d += a * bcast(b.lo)
#define PK_FMA_S1B0(d, a, b) \
    asm("v_pk_fma_f32 %0, %1, %2, %0 op_sel:[0,0,0] op_sel_hi:[1,0,1]" \
        : "+v"(d) : "v"(a), "v"(b))
// d += a * bcast(b.hi)
#define PK_FMA_S1B1(d, a, b) \
    asm("v_pk_fma_f32 %0, %1, %2, %0 op_sel:[0,1,0] op_sel_hi:[1,1,1]" \
        : "+v"(d) : "v"(a), "v"(b))
// d = a * 0.5 (both halves)
#define PK_MUL_HALF(d, a) \
    asm("v_pk_mul_f32 %0, %1, 0.5 op_sel:[0,0] op_sel_hi:[1,0]" \
        : "=v"(d) : "v"(a))

__global__ __launch_bounds__(256)
void sig_accum_kernel(
    const float* __restrict__ original,
    const float* __restrict__ generated,
    const int* __restrict__ sample_idx,
    float* __restrict__ ws,
    float* __restrict__ accinit,   // non-null: block 0 zeroes DTOT+2 floats
    int nrep, int store_mode)
{
    const int tid  = threadIdx.x;
    const int bp   = blockIdx.x;         // 0 .. 2*NPAIR-1
    const int b    = bp >> 1;            // pair index
    const int pass = bp & 1;             // 0 = generated (-), 1 = original (+)
    const float sgn = pass ? 1.0f : -1.0f;

    __shared__ __align__(16) float s_dx[NSTEP * DXROW];   // 12240 B (row-major)
    __shared__ __align__(16) f32x2 s_pj[5 * PSTRIDE];     // 10320 B
    __shared__ __align__(16) f32x2 s_pk[5 * PSTRIDE];     // 10320 B

    if (accinit != nullptr && bp == 0) {
        for (int i = tid; i < DTOT + 2; i += 256) accinit[i] = 0.0f;
    }

    const float* path = pass
        ? original + (size_t)sample_idx[b] * PATH_ELEMS
        : generated + (size_t)b * PATH_ELEMS;

    for (int idx = tid; idx < DX_ELEMS; idx += 256) {
        int t = idx / C_DIM, c = idx - t * C_DIM;
        s_dx[t * DXROW + c] = path[idx + C_DIM] - path[idx];
    }
    __syncthreads();

    // Pair-layout staging (reads row-major LDS, writes column-pair LDS).
    for (int idx = tid; idx < NSTEP * 5; idx += 256) {
        const int t = idx / 5, k = idx - 5 * t;
        f32x2 pk;
        pk.x = s_dx[t * DXROW + k];
        pk.y = s_dx[t * DXROW + k + 5];
        s_pk[k * PSTRIDE + t] = pk;
        f32x2 pj;
        pj.x = s_dx[t * DXROW + 2 * k];
        pj.y = s_dx[t * DXROW + 2 * k + 1];
        s_pj[k * PSTRIDE + t] = pj;
    }
    __syncthreads();

    const int mbase = 2 * tid;               // valid tid<250
    const int k0  = mbase / 100;             // 0..4
    const int ij0 = mbase - k0 * 100;        // even
    const int ia  = ij0 / 10;
    const int j0  = ij0 - ia * 10;           // even -> (j0, j0+1) same decade
    const int j2  = j0 >> 1;                 // 0..4

    float s1a = 0.0f;
    f32x2 s2p = {0.0f, 0.0f};                 // (q0, q1)
    f32x2 s3p[2] = {{0.0f, 0.0f}, {0.0f, 0.0f}};  // [0]=(q0,q1)@k0, [1]=@k1
    f32x2 acc2[4][5];                         // [0]=q0k0 [1]=q1k0 [2]=q0k1 [3]=q1k1
    #pragma unroll
    for (int r = 0; r < 4; ++r)
        #pragma unroll
        for (int i = 0; i < 5; ++i) acc2[r][i] = (f32x2){0.0f, 0.0f};

    if (tid < 250) {
        const float* vrow = s_dx;
        const f32x2* pjc = &s_pj[j2 * PSTRIDE];
        const f32x2* pkc = &s_pk[k0 * PSTRIDE];

        // One Chen step given (vjp, vkp) and the uniform row at vrow.
        #define CHEN_STEP(VJP, VKP)                                         \
        {                                                                   \
            const f32x4 va = *(const f32x4*)(vrow);                         \
            const f32x4 vb = *(const f32x4*)(vrow + 4);                     \
            const f32x2 vc = *(const f32x2*)(vrow + 8);                     \
            const float via = vrow[ia];                                     \
            const f32x2 vv2[5] = {va.xy, va.zw, vb.xy, vb.zw, vc};          \
            const float t3  = fmaf(via, 0.5f, s1a);                         \
            const float t1b = fmaf(via, 0.25f, s1a) * (1.0f / 3.0f);        \
            const float t2b = fmaf(via, (1.0f / 3.0f), s1a) * 0.5f;         \
            f32x2 pA; pA.x = t1b; pA.y = t2b;                               \
            f32x2 pT; pT.x = t3;  pT.y = t3;                                \
            f32x2 vkhp;                                                     \
            PK_MUL_HALF(vkhp, (VKP));                                       \
            f32x2 a2p, b2p;                                                 \
            PK_FMA_B0N(a2p, pA, (VJP), s2p);                                \
            PK_FMA_B1N(b2p, pA, (VJP), s2p);                                \
            PK_FMA_B0(s2p, pT, (VJP));                                      \
            f32x2 a3xp, a3yp;                                               \
            PK_FMA_S1B0N(a3xp, a2p, vkhp, s3p[0]);                          \
            PK_FMA_S1B1N(a3yp, a2p, vkhp, s3p[1]);                          \
            PK_FMA_S1B0(s3p[0], b2p, (VKP));                                \
            PK_FMA_S1B1(s3p[1], b2p, (VKP));                                \
            _Pragma("unroll")                                               \
            for (int i = 0; i < 5; ++i) {                                   \
                PK_FMA_B0(acc2[0][i], a3xp, vv2[i]);                        \
                PK_FMA_B1(acc2[1][i], a3xp, vv2[i]);                        \
                PK_FMA_B0(acc2[2][i], a3yp, vv2[i]);                        \
                PK_FMA_B1(acc2[3][i], a3yp, vv2[i]);                        \
            }                                                               \
            s1a += via;                                                     \
            vrow += DXROW;                                                  \
        }

        #pragma unroll 1
        for (int t = 0; t < NSTEP - 1; t += 2) {
            // 2-step b128 pair loads (16B-aligned: t even, PSTRIDE even).
            const f32x4 pj2 = *(const f32x4*)(pjc + t);   // {vjp_t, vjp_t1}
            const f32x4 pk2 = *(const f32x4*)(pkc + t);   // {vkp_t, vkp_t1}
            CHEN_STEP(pj2.xy, pk2.xy)
            CHEN_STEP(pj2.zw, pk2.zw)
        }
        {   // tail step t = 254
            const f32x2 vjp = pjc[NSTEP - 1];
            const f32x2 vkp = pkc[NSTEP - 1];
            CHEN_STEP(vjp, vkp)
        }
        #undef CHEN_STEP
    }

    // ---- Epilogue: signed single-path row ----
    if (store_mode) {
        float* row = ws + (size_t)bp * DTOT;
        if (tid < D1)
            row[tid] = sgn * (path[(T_LEN - 1) * C_DIM + tid] - path[tid]);
        if (tid < 50) {       // k0 == 0 threads own ij0 = 2*tid
            row[D1 + ij0]     = sgn * s2p[0];
            row[D1 + ij0 + 1] = sgn * s2p[1];
        }
        if (tid < 250) {
            #pragma unroll
            for (int ch = 0; ch < 2; ++ch) {          // ch=0 -> k0, ch=1 -> k0+5
                const int kk = k0 + 5 * ch;
                #pragma unroll
                for (int q = 0; q < 2; ++q) {
                    const int idx3 = (ij0 + q) * 10 + kk;
                    row[D1 + D2 + idx3] = sgn * s3p[ch][q];
                    float* p4 = row + D1 + D2 + D3 + (size_t)idx3 * 10;
                    #pragma unroll
                    for (int i = 0; i < 5; ++i)
                        *(f32x2*)&p4[2 * i] = sgn * acc2[ch * 2 + q][i];
                }
            }
        }
    } else {
        float* base = ws + (size_t)(b % nrep) * DTOT;
        if (tid < D1)
            atomicAdd(&base[tid],
                      sgn * (path[(T_LEN - 1) * C_DIM + tid] - path[tid]));
        if (tid < 50) {
            atomicAdd(&base[D1 + ij0],     sgn * s2p[0]);
            atomicAdd(&base[D1 + ij0 + 1], sgn * s2p[1]);
        }
        if (tid < 250) {
            #pragma unroll
            for (int ch = 0; ch < 2; ++ch) {
                const int kk = k0 + 5 * ch;
                #pragma unroll
                for (int q = 0; q < 2; ++q) {
                    const int idx3 = (ij0 + q) * 10 + kk;
                    atomicAdd(&base[D1 + D2 + idx3], sgn * s3p[ch][q]);
                    #pragma unroll
                    for (int l = 0; l < 10; ++l)
                        atomicAdd(&base[D1 + D2 + D3 + idx3 * 10 + l],
                                  sgn * acc2[ch * 2 + q][l >> 1][l & 1]);
                }
            }
        }
    }
}

// Stage 1: block sums 32 rows for a float2 d-tile (coalesced), atomically
// accumulates into accvec[DTOT]. Grid: (ceil(5555/256), nrows/32). NO fences.
__global__ __launch_bounds__(256) void sig_sum_kernel(
    const float* __restrict__ ws, float* __restrict__ accvec)
{
    const int d2 = blockIdx.x * 256 + threadIdx.x;   // DTOT/2 = 5555
    if (d2 >= DTOT / 2) return;
    const float* p = ws + (size_t)(blockIdx.y * 32) * DTOT + 2 * d2;
    float sx = 0.0f, sy = 0.0f;
    #pragma unroll
    for (int r = 0; r < 32; ++r) {
        const float2 v = *(const float2*)(p + (size_t)r * DTOT);
        sx += v.x; sy += v.y;
    }
    atomicAdd(&accvec[2 * d2], sx);
    atomicAdd(&accvec[2 * d2 + 1], sy);
}

// Stage 2: sum of squares -> sumsq; last block writes the norm.
__global__ __launch_bounds__(256) void sig_sumsq_kernel(
    const float* __restrict__ accvec, float* __restrict__ sumsq,
    unsigned int* __restrict__ counter, float* __restrict__ out, int nblocks)
{
    const int d = blockIdx.x * 256 + threadIdx.x;
    float s = 0.0f;
    if (d < DTOT) { float v = accvec[d]; s = v * v; }
    for (int off = 32; off > 0; off >>= 1) s += __shfl_down(s, off, 64);
    __shared__ float red[4];
    __shared__ unsigned int lastflag;
    if ((threadIdx.x & 63) == 0) red[threadIdx.x >> 6] = s;
    __syncthreads();
    if (threadIdx.x == 0) {
        atomicAdd(sumsq, red[0] + red[1] + red[2] + red[3]);
        __threadfence();
        lastflag = (atomicAdd(counter, 1u) == (unsigned int)(nblocks - 1));
    }
    __syncthreads();
    if (threadIdx.x == 0 && lastflag) {
        __threadfence();
        out[0] = sqrtf(*(volatile float*)sumsq) * (1.0f / (float)BSZ);
    }
}

// Fallback reduce for small-ws atomic-replica modes.
__global__ __launch_bounds__(256) void sig_reduce_kernel(
    const float* __restrict__ ws, int nrows, float* __restrict__ sumsq,
    unsigned int* __restrict__ counter, float* __restrict__ out, int nblocks)
{
    const int d = blockIdx.x * 256 + threadIdx.x;
    float s = 0.0f;
    if (d < DTOT) {
        for (int r = 0; r < nrows; ++r) s += ws[(size_t)r * DTOT + d];
        s = s * s;
    }
    for (int off = 32; off > 0; off >>= 1) s += __shfl_down(s, off, 64);
    __shared__ float red[4];
    __shared__ unsigned int lastflag;
    if ((threadIdx.x & 63) == 0) red[threadIdx.x >> 6] = s;
    __syncthreads();
    if (threadIdx.x == 0) {
        atomicAdd(sumsq, red[0] + red[1] + red[2] + red[3]);
        __threadfence();
        lastflag = (atomicAdd(counter, 1u) == (unsigned int)(nblocks - 1));
    }
    __syncthreads();
    if (threadIdx.x == 0 && lastflag) {
        __threadfence();
        out[0] = sqrtf(*(volatile float*)sumsq) * (1.0f / (float)BSZ);
    }
}

extern "C" void kernel_launch(void* const* d_in, const int* in_sizes, int n_in,
                              void* d_out, int out_size, void* d_ws, size_t ws_size,
                              hipStream_t stream) {
    const float* original   = (const float*)d_in[0];
    const float* generated  = (const float*)d_in[1];
    const int*   sample_idx = (const int*)d_in[2];
    float* out = (float*)d_out;
    float* ws  = (float*)d_ws;

    // Layouts:
    //  split: rows [0, 2N*DTOT), accvec [+DTOT), sumsq [+1), counter [+1)
    //  store: rows [0, N*DTOT),  accvec [+DTOT), sumsq [+1), counter [+1)
    const size_t need_split = ((size_t)(2 * NPAIR + 1) * DTOT + 2) * sizeof(float);
    const size_t need_store = ((size_t)(NPAIR + 1) * DTOT + 2) * sizeof(float);

    if (ws_size >= need_split) {
        // Primary: 3 dispatches. accum block 0 zero-inits accvec+sumsq+counter.
        float* accvec = ws + (size_t)2 * NPAIR * DTOT;
        float* sumsq  = accvec + DTOT;
        unsigned int* counter = (unsigned int*)(sumsq + 1);
        sig_accum_kernel<<<2 * NPAIR, 256, 0, stream>>>(original, generated,
                                                        sample_idx, ws, accvec,
                                                        1, 1);
        dim3 g1((DTOT / 2 + 255) / 256, 2 * NPAIR / 32);
        sig_sum_kernel<<<g1, 256, 0, stream>>>(ws, accvec);
        const int nb2 = (DTOT + 255) / 256;
        sig_sumsq_kernel<<<nb2, 256, 0, stream>>>(accvec, sumsq, counter, out, nb2);
    } else if (ws_size >= need_store) {
        // Pair-atomic rows + separate reduction.
        float* accvec = ws + (size_t)NPAIR * DTOT;
        float* sumsq  = accvec + DTOT;
        unsigned int* counter = (unsigned int*)(sumsq + 1);
        hipMemsetAsync(ws, 0, need_store, stream);
        sig_accum_kernel<<<2 * NPAIR, 256, 0, stream>>>(original, generated,
                                                        sample_idx, ws, nullptr,
                                                        NPAIR, 0);
        dim3 g1((DTOT / 2 + 255) / 256, NPAIR / 32);
        sig_sum_kernel<<<g1, 256, 0, stream>>>(ws, accvec);
        const int nb2 = (DTOT + 255) / 256;
        sig_sumsq_kernel<<<nb2, 256, 0, stream>>>(accvec, sumsq, counter, out, nb2);
    } else {
        int nrep = 1;
        if (ws_size >= ((size_t)64 * DTOT + 2) * sizeof(float)) nrep = 64;
        else if (ws_size >= ((size_t)8 * DTOT + 2) * sizeof(float)) nrep = 8;
        float* sumsq = ws + (size_t)nrep * DTOT;
        unsigned int* counter = (unsigned int*)(sumsq + 1);
        hipMemsetAsync(ws, 0, ((size_t)nrep * DTOT + 2) * sizeof(float), stream);
        sig_accum_kernel<<<2 * NPAIR, 256, 0, stream>>>(original, generated,
                                                        sample_idx, ws, nullptr,
                                                        nrep, 0);
        const int nb2 = (DTOT + 255) / 256;
        sig_reduce_kernel<<<nb2, 256, 0, stream>>>(ws, nrep, sumsq, counter, out, nb2);
    }
}